// Round 11
// baseline (9439.092 us; speedup 1.0000x reference)
//
#include <hip/hip_runtime.h>

// ============================================================================
// 2-layer tanh RNN, B=32, S=2048, D=H=O=512.
//  r10 = r6 skeleton (16 fused WGs, self-tagged rings, fire-and-forget
//        stores, retry-capped polls) + low-contention detection:
//   - sentinel gating: each wave polls 32 tagged sentinel DWORDS (one per
//     producer WG x finisher wave; lanes 0-31 watch h0(p-1), lanes 32-63
//     watch h1(p-2)) instead of hammering its full 4KB fragment set.
//     ~500x less poll traffic -> uncached RTs relax toward uncontended.
//   - 2-deep pipelined sentinel sampling (vmcnt(1) alternation): sampling
//     period ~RT/2. Sentinel regs kept live past the final drain.
//   - after the gate: fragment loads issued once, single vmcnt(0), tags
//     verified (r6 backstop); stale -> r6 poll_frag fallback. Caps latch
//     'bad' (fast fail, never hangs).
// ============================================================================

typedef short v8s __attribute__((ext_vector_type(8)));
typedef int   v4i __attribute__((ext_vector_type(4)));
typedef float v4f __attribute__((ext_vector_type(4)));

#define B_  32
#define S_  2048
#define DH  512
#define SLOT32 16384                      // u32 per ring slot (32 x 512)
#define EPOCH4(q) ((unsigned)(((q) >> 2) & 7))

// ws layout (bytes)
#define BIAS_OFF  0                       // [2][512] f32 (b_ih + b_hh)
#define H0_OFF    8192                    // 4 slots x 64KB packed u32
#define H1_OFF    (H0_OFF + 4 * 65536)
#define WOUT_OFF  (H1_OFF + 4 * 65536)    // w_out bf16 [512][512]
#define WIH0_OFF  (WOUT_OFF + 524288)     // w_ih[0] bf16 [512][512]

#define PART_BYTES (8 * 3 * 4 * 64 * 16)  // 96KB LDS partials

static __device__ __forceinline__ unsigned short f2bf(float f) {  // RNE
  unsigned int u = __builtin_bit_cast(unsigned int, f);
  u += 0x7fffu + ((u >> 16) & 1u);
  return (unsigned short)(u >> 16);
}
static __device__ __forceinline__ float bf2f(unsigned short h) {
  return __builtin_bit_cast(float, ((unsigned int)h) << 16);
}
static __device__ __forceinline__ unsigned packh(float f, unsigned ep) {
  unsigned short hv = f2bf(f);
  unsigned short lv = f2bf(f - bf2f(hv));
  return ((unsigned)hv << 16) | ((unsigned)lv & 0xFFF8u) | ep;
}
static __device__ __forceinline__ v8s pack8(float4 f0, float4 f1) {
  v8s r;
  r[0] = (short)f2bf(f0.x); r[1] = (short)f2bf(f0.y);
  r[2] = (short)f2bf(f0.z); r[3] = (short)f2bf(f0.w);
  r[4] = (short)f2bf(f1.x); r[5] = (short)f2bf(f1.y);
  r[6] = (short)f2bf(f1.z); r[7] = (short)f2bf(f1.w);
  return r;
}
static __device__ __forceinline__ float fast_tanh(float v) {
  float c = fminf(15.f, fmaxf(-15.f, v));
  float e = __expf(2.f * c);
  return (e - 1.f) * __builtin_amdgcn_rcpf(e + 1.f);
}

// ---- device-scope (MALL) accessors ----------------------------------------
static __device__ __forceinline__ v4i ld16v(const unsigned* p) {
  v4i r;
  asm volatile("global_load_dwordx4 %0, %1, off sc1"
               : "=v"(r) : "v"(p) : "memory");
  return r;
}
static __device__ __forceinline__ float ld4(const void* p) {  // cached
  float r;
  asm volatile("global_load_dword %0, %1, off"
               : "=v"(r) : "v"(p) : "memory");
  return r;
}
static __device__ __forceinline__ unsigned ld4u(const void* p) {  // sc1, unwaited
  unsigned r;
  asm volatile("global_load_dword %0, %1, off sc1"
               : "=v"(r) : "v"(p) : "memory");
  return r;
}
static __device__ __forceinline__ void st32u(void* p, unsigned v) {
  asm volatile("global_store_dword %0, %1, off sc1"
               :: "v"(p), "v"(v) : "memory");
}
#define WAITN0() do { asm volatile("s_waitcnt vmcnt(0)" ::: "memory"); \
    __builtin_amdgcn_sched_barrier(0); } while (0)
#define WAIT1() do { asm volatile("s_waitcnt vmcnt(1)" ::: "memory"); \
    __builtin_amdgcn_sched_barrier(0); } while (0)

// Full-fragment poll fallback (r6 mechanism).
static __device__ __forceinline__ void poll_frag(const unsigned* b, unsigned ep,
                                                 bool* bad, v4i* o0, v4i* o1,
                                                 v4i* o2, v4i* o3) {
  v4i a0, a1, a2, a3;
  int t = 0;
  for (;;) {
    a0 = ld16v(b); a1 = ld16v(b + 4); a2 = ld16v(b + 32); a3 = ld16v(b + 36);
    WAITN0();
    if (*bad) break;
    unsigned d = 0;
    #pragma unroll
    for (int j = 0; j < 4; ++j)
      d |= ((unsigned)a0[j] ^ ep) | ((unsigned)a1[j] ^ ep)
         | ((unsigned)a2[j] ^ ep) | ((unsigned)a3[j] ^ ep);
    if (__all((d & 7u) == 0u)) break;
    if (++t > (1 << 15)) { *bad = true; break; }
  }
  *o0 = a0; *o1 = a1; *o2 = a2; *o3 = a3;
}
static __device__ __forceinline__ void unp(v4i a, v4i b, v8s* hi, v8s* lo) {
  v8s h, l;
  #pragma unroll
  for (int j = 0; j < 4; ++j) {
    unsigned ua = (unsigned)a[j], ub = (unsigned)b[j];
    h[j]     = (short)(ua >> 16);   l[j]     = (short)(ua & 0xFFF8u);
    h[4 + j] = (short)(ub >> 16);   l[4 + j] = (short)(ub & 0xFFF8u);
  }
  *hi = h; *lo = l;
}

// ---------------------------------------------------------------------------
__global__ void rnn_init(const float* __restrict__ hidden,
                         const float* __restrict__ b_ih,
                         const float* __restrict__ b_hh,
                         const float* __restrict__ w_out,
                         const float* __restrict__ w_ih,
                         float* __restrict__ bias,
                         unsigned* __restrict__ h0ring,
                         unsigned* __restrict__ h1ring,
                         unsigned short* __restrict__ woutbf,
                         unsigned short* __restrict__ wih0bf) {
  int i = blockIdx.x * blockDim.x + threadIdx.x;
  int nth = gridDim.x * blockDim.x;
  for (int t = i; t < 1024; t += nth) bias[t] = b_ih[t] + b_hh[t];
  for (int t = i; t < 2 * B_ * DH; t += nth) {     // initial h -> slot 3, tag 7
    int l = t >> 14;
    int off = t & 16383;
    unsigned* ring = l ? h1ring : h0ring;
    ring[3 * SLOT32 + off] = packh(hidden[t], 7u);
  }
  for (int t = i; t < 512 * 512; t += nth) {
    woutbf[t] = f2bf(w_out[t]);
    wih0bf[t] = f2bf(w_ih[t]);
  }
}

// ---------------------------------------------------------------------------
// Bulk projection: dst[r][:] = src[r][:] @ wb^T + bias (64 rows/WG, in-place ok)
__global__ __launch_bounds__(512) void proj64(
    const float* __restrict__ src,
    float* __restrict__ dst,
    const unsigned short* __restrict__ wb,
    const float* __restrict__ bias) {
  __shared__ unsigned short lds[64 * 512];
  const int tid = threadIdx.x;
  const int wid = tid >> 6;
  const int lane = tid & 63;
  const size_t row0 = (size_t)blockIdx.x * 64;

  #pragma unroll
  for (int it = 0; it < 8; ++it) {
    int c = it * 512 + tid;
    int row = c >> 6;
    int col8 = c & 63;
    const float4* s4 = (const float4*)(src + (row0 + row) * DH + col8 * 8);
    float4 f0 = s4[0], f1 = s4[1];
    v8s t = pack8(f0, f1);
    int byteoff = row * 1024 + ((col8 * 16) ^ ((row & 7) << 4));
    *(v8s*)((char*)lds + byteoff) = t;
  }
  __syncthreads();

  const int l15 = lane & 15;
  const int kq = (lane >> 4) * 8;

  for (int nt = wid; nt < 32; nt += 8) {
    v4f acc[4];
    #pragma unroll
    for (int mt = 0; mt < 4; ++mt) acc[mt] = (v4f){0.f, 0.f, 0.f, 0.f};
    const unsigned short* wr = wb + (size_t)(nt * 16 + l15) * 512;
    #pragma unroll
    for (int ks = 0; ks < 16; ++ks) {
      int kk = ks * 32 + kq;
      v8s bfrag = *(const v8s*)(wr + kk);
      #pragma unroll
      for (int mt = 0; mt < 4; ++mt) {
        int row = mt * 16 + l15;
        int byteoff = row * 1024 + ((kk * 2) ^ ((row & 7) << 4));
        v8s afrag = *(const v8s*)((char*)lds + byteoff);
        acc[mt] = __builtin_amdgcn_mfma_f32_16x16x32_bf16(afrag, bfrag, acc[mt], 0, 0, 0);
      }
    }
    float bo = bias[nt * 16 + l15];
    #pragma unroll
    for (int mt = 0; mt < 4; ++mt)
      #pragma unroll
      for (int r = 0; r < 4; ++r) {
        int row = mt * 16 + (lane >> 4) * 4 + r;
        int col = nt * 16 + l15;
        dst[(row0 + row) * DH + col] = acc[mt][r] + bo;
      }
  }
}

// ---------------------------------------------------------------------------
// Fused persistent kernel. wg = mh*8 + fs. 8 waves = 8 K-eighths.
// Phase p: GEMM0 Whh0*h0(p-1) -> h0(p); GEMM1 Wih1*h0(p-1) and
// GEMM2 Whh1*h1(p-2) -> h1(p-1). Waves 0-3 finish (reduce+tanh+store).
__global__ __launch_bounds__(512) void rnn_fused(
    const float* __restrict__ z0,     // d_out: Z0 (overwritten by dout)
    const float* __restrict__ w_ih,
    const float* __restrict__ w_hh,
    const float* __restrict__ bias,
    unsigned* __restrict__ h0ring,
    unsigned* __restrict__ h1ring,
    float* __restrict__ dout) {
  extern __shared__ char smem[];
  v4f* part = (v4f*)smem;               // [8][3][4][64]

  const int wg = blockIdx.x;
  const int mh = wg >> 3;               // batch half
  const int fs = wg & 7;                // feature slice (64 feats)

  const int tid = threadIdx.x;
  const int wid = tid >> 6;             // K-eighth
  const int lane = tid & 63;
  const int l15 = lane & 15;
  const int kq = (lane >> 4) * 8;
  const int q4 = (lane >> 4) * 4;

  // resident weights: wfrag[g][n][ks], g: {w_hh0, w_ih1, w_hh1}
  v8s wfrag[3][4][2];
  {
    const float* wsrcs[3] = { w_hh, w_ih + 512 * 512, w_hh + 512 * 512 };
    #pragma unroll
    for (int g = 0; g < 3; ++g)
      #pragma unroll
      for (int n = 0; n < 4; ++n)
        #pragma unroll
        for (int ks = 0; ks < 2; ++ks) {
          const float* srow = wsrcs[g] +
              (size_t)(fs * 64 + n * 16 + l15) * 512 + wid * 64 + ks * 32 + kq;
          wfrag[g][n][ks] = pack8(*(const float4*)srow, *(const float4*)(srow + 4));
        }
  }
  const int nf = wid & 3;               // finisher n-tile (wid<4)
  const float bias1v = bias[512 + fs * 64 + nf * 16 + l15];
  const size_t abase = (size_t)(mh * 16 + l15) * 512 + wid * 64 + kq;
  const int featf = fs * 64 + nf * 16 + l15;

  // per-lane sentinel offset: producer (fs_s, nf_s) last-issued dword
  const int fs_s = (lane >> 2) & 7, nf_s = lane & 3;
  const size_t soff = (size_t)(mh * 16 + 15) * 512 + fs_s * 64 + nf_s * 16 + 15;

  bool bad = false;

  for (int p = 0; p <= S_; ++p) {
    const unsigned ep0 = (p == 0) ? 7u : EPOCH4(p - 1);
    const unsigned ep1 = (p == 1) ? 7u : EPOCH4(p - 2);   // meaningful p>=1
    const unsigned* h0b = h0ring + (size_t)((p + 3) & 3) * SLOT32 + abase;
    const unsigned* h1b = h1ring + (size_t)((p + 2) & 3) * SLOT32 + abase;

    // ---- 2-deep pipelined sentinel poll (lanes<32: h0, lanes>=32: h1) ----
    const bool useh1 = (p >= 1) && (lane >= 32);
    const unsigned* sp = useh1
        ? (h1ring + (size_t)((p + 2) & 3) * SLOT32 + soff)
        : (h0ring + (size_t)((p + 3) & 3) * SLOT32 + soff);
    const unsigned eps = useh1 ? ep1 : ep0;

    unsigned sa = ld4u(sp);
    unsigned sb = ld4u(sp);
    {
      int t = 0;
      for (;;) {
        WAIT1();                               // sa complete (sb in flight)
        if (__all(((sa ^ eps) & 7u) == 0u) || bad) break;
        sa = ld4u(sp);
        WAIT1();                               // sb complete (sa in flight)
        if (__all(((sb ^ eps) & 7u) == 0u) || bad) break;
        sb = ld4u(sp);
        if (++t > (1 << 16)) { bad = true; break; }
      }
    }

    // ---- fragment + z0 loads, one drain ----------------------------------
    v4i A0 = ld16v(h0b), A1 = ld16v(h0b + 4);
    v4i A2 = ld16v(h0b + 32), A3 = ld16v(h0b + 36);
    v4i B0, B1, B2, B3;
    if (p >= 1) {
      B0 = ld16v(h1b); B1 = ld16v(h1b + 4);
      B2 = ld16v(h1b + 32); B3 = ld16v(h1b + 36);
    }
    float zp[4];
    if (wid < 4) {
      const int pz = (p < S_) ? p : (S_ - 1);
      #pragma unroll
      for (int r = 0; r < 4; ++r)
        zp[r] = ld4(z0 + ((size_t)(mh * 16 + q4 + r) * S_ + pz) * DH + featf);
    }
    WAITN0();
    asm volatile("" :: "v"(sa), "v"(sb));      // sentinel regs live past drain

    // ---- tag verify (backstop); rare fallback ----------------------------
    {
      unsigned d = 0;
      #pragma unroll
      for (int j = 0; j < 4; ++j)
        d |= ((unsigned)A0[j] ^ ep0) | ((unsigned)A1[j] ^ ep0)
           | ((unsigned)A2[j] ^ ep0) | ((unsigned)A3[j] ^ ep0);
      if (!__all((d & 7u) == 0u))
        poll_frag(h0b, ep0, &bad, &A0, &A1, &A2, &A3);
    }
    if (p >= 1) {
      unsigned d = 0;
      #pragma unroll
      for (int j = 0; j < 4; ++j)
        d |= ((unsigned)B0[j] ^ ep1) | ((unsigned)B1[j] ^ ep1)
           | ((unsigned)B2[j] ^ ep1) | ((unsigned)B3[j] ^ ep1);
      if (!__all((d & 7u) == 0u))
        poll_frag(h1b, ep1, &bad, &B0, &B1, &B2, &B3);
    }

    v8s h0h0, h0l0, h0h1, h0l1;
    unp(A0, A1, &h0h0, &h0l0);
    unp(A2, A3, &h0h1, &h0l1);

    v4f acc0[4], acc1[4], acc2[4];
    #pragma unroll
    for (int n = 0; n < 4; ++n) {
      acc0[n] = (v4f){0.f, 0.f, 0.f, 0.f};
      acc1[n] = (v4f){0.f, 0.f, 0.f, 0.f};
      acc2[n] = (v4f){0.f, 0.f, 0.f, 0.f};
    }
    #pragma unroll
    for (int n = 0; n < 4; ++n) {
      acc0[n] = __builtin_amdgcn_mfma_f32_16x16x32_bf16(h0h0, wfrag[0][n][0], acc0[n], 0, 0, 0);
      acc0[n] = __builtin_amdgcn_mfma_f32_16x16x32_bf16(h0l0, wfrag[0][n][0], acc0[n], 0, 0, 0);
      acc0[n] = __builtin_amdgcn_mfma_f32_16x16x32_bf16(h0h1, wfrag[0][n][1], acc0[n], 0, 0, 0);
      acc0[n] = __builtin_amdgcn_mfma_f32_16x16x32_bf16(h0l1, wfrag[0][n][1], acc0[n], 0, 0, 0);
      acc1[n] = __builtin_amdgcn_mfma_f32_16x16x32_bf16(h0h0, wfrag[1][n][0], acc1[n], 0, 0, 0);
      acc1[n] = __builtin_amdgcn_mfma_f32_16x16x32_bf16(h0l0, wfrag[1][n][0], acc1[n], 0, 0, 0);
      acc1[n] = __builtin_amdgcn_mfma_f32_16x16x32_bf16(h0h1, wfrag[1][n][1], acc1[n], 0, 0, 0);
      acc1[n] = __builtin_amdgcn_mfma_f32_16x16x32_bf16(h0l1, wfrag[1][n][1], acc1[n], 0, 0, 0);
    }
    if (p >= 1) {
      v8s h1h0, h1l0, h1h1, h1l1;
      unp(B0, B1, &h1h0, &h1l0);
      unp(B2, B3, &h1h1, &h1l1);
      #pragma unroll
      for (int n = 0; n < 4; ++n) {
        acc2[n] = __builtin_amdgcn_mfma_f32_16x16x32_bf16(h1h0, wfrag[2][n][0], acc2[n], 0, 0, 0);
        acc2[n] = __builtin_amdgcn_mfma_f32_16x16x32_bf16(h1l0, wfrag[2][n][0], acc2[n], 0, 0, 0);
        acc2[n] = __builtin_amdgcn_mfma_f32_16x16x32_bf16(h1h1, wfrag[2][n][1], acc2[n], 0, 0, 0);
        acc2[n] = __builtin_amdgcn_mfma_f32_16x16x32_bf16(h1l1, wfrag[2][n][1], acc2[n], 0, 0, 0);
      }
    }

    // ---- K-reduction partials ---------------------------------------------
    #pragma unroll
    for (int n = 0; n < 4; ++n) {
      part[((wid * 3 + 0) * 4 + n) * 64 + lane] = acc0[n];
      part[((wid * 3 + 1) * 4 + n) * 64 + lane] = acc1[n];
      part[((wid * 3 + 2) * 4 + n) * 64 + lane] = acc2[n];
    }
    __syncthreads();

    // ---- finishers: reduce, tanh, pack+tag, fire-and-forget stores --------
    if (wid < 4) {
      v4f s0 = {0.f,0.f,0.f,0.f}, s1 = {0.f,0.f,0.f,0.f}, s2 = {0.f,0.f,0.f,0.f};
      #pragma unroll
      for (int w = 0; w < 8; ++w) {
        s0 += part[((w * 3 + 0) * 4 + nf) * 64 + lane];
        s1 += part[((w * 3 + 1) * 4 + nf) * 64 + lane];
        s2 += part[((w * 3 + 2) * 4 + nf) * 64 + lane];
      }
      float h0v[4], h1v[4];
      #pragma unroll
      for (int r = 0; r < 4; ++r) {
        h0v[r] = fast_tanh(zp[r] + s0[r]);
        h1v[r] = fast_tanh(s1[r] + s2[r] + bias1v);
      }
      if (p < S_) {                                   // h0(p), tag (p>>2)&7
        const unsigned ep = EPOCH4(p);
        unsigned* dst = h0ring + (size_t)(p & 3) * SLOT32;
        #pragma unroll
        for (int r = 0; r < 4; ++r)
          st32u(dst + (size_t)(mh * 16 + q4 + r) * 512 + featf, packh(h0v[r], ep));
      }
      if (p >= 1) {                                   // h1(p-1), tag ((p-1)>>2)&7
        const unsigned ep = EPOCH4(p - 1);
        unsigned* dst = h1ring + (size_t)((p - 1) & 3) * SLOT32;
        #pragma unroll
        for (int r = 0; r < 4; ++r) {
          st32u(dst + (size_t)(mh * 16 + q4 + r) * 512 + featf, packh(h1v[r], ep));
          dout[((size_t)(mh * 16 + q4 + r) * S_ + (p - 1)) * DH + featf] = h1v[r];
        }
      }
    }
    __syncthreads();   // keep LDS partials stable until finishers consumed them
  }
}

// ---------------------------------------------------------------------------
extern "C" void kernel_launch(void* const* d_in, const int* in_sizes, int n_in,
                              void* d_out, int out_size, void* d_ws, size_t ws_size,
                              hipStream_t stream) {
  const float* x      = (const float*)d_in[0];
  const float* hidden = (const float*)d_in[1];
  const float* w_ih   = (const float*)d_in[2];
  const float* w_hh   = (const float*)d_in[3];
  const float* b_ih   = (const float*)d_in[4];
  const float* b_hh   = (const float*)d_in[5];
  const float* w_out  = (const float*)d_in[6];
  const float* b_out  = (const float*)d_in[7];
  float* out = (float*)d_out;

  char* wsb = (char*)d_ws;
  float* bias            = (float*)(wsb + BIAS_OFF);
  unsigned* h0ring       = (unsigned*)(wsb + H0_OFF);
  unsigned* h1ring       = (unsigned*)(wsb + H1_OFF);
  unsigned short* woutbf = (unsigned short*)(wsb + WOUT_OFF);
  unsigned short* wih0bf = (unsigned short*)(wsb + WIH0_OFF);

  rnn_init<<<256, 256, 0, stream>>>(hidden, b_ih, b_hh, w_out, w_ih,
                                    bias, h0ring, h1ring, woutbf, wih0bf);
  // Z0 = x @ w_ih0^T + (b_ih0 + b_hh0) -> d_out
  proj64<<<(B_ * S_) / 64, 512, 0, stream>>>(x, out, wih0bf, bias);
  rnn_fused<<<16, 512, PART_BYTES, stream>>>(out, w_ih, w_hh, bias,
                                             h0ring, h1ring, out);
  // out = h1 @ w_out^T + b_out (in place)
  proj64<<<(B_ * S_) / 64, 512, 0, stream>>>(out, out, woutbf, b_out);
}

// Round 12
// 8495.927 us; speedup vs baseline: 1.1110x; 1.1110x over previous
//
#include <hip/hip_runtime.h>

// ============================================================================
// 2-layer tanh RNN, B=32, S=2048, D=H=O=512.
//  r11 = r6 skeleton (best: 6.95ms) + producer store coalescing:
//   - finisher remap: wave w owns batches 4w..4w+3, lane = feature. Same 24
//     ds_read_b128 partial reads (v4f elements = the 4 batches), but ring и
//     dout stores become contiguous 256B wave-stores (4/ring vs 16 scattered
//     64B runs) -> faster store-queue drain + MALL injection (attacks V).
//   - h1 fragments early-issued before the h0 poll (drained inside it,
//     tag-verified after; rare fallback) -> no serial h1 leg.
//   - z0 loads moved off the poll path (issued post-poll, coalesced,
//     drained at finisher start).
//  r10's serial sentinel gate reverted (it added a full RT: +1.07us/step).
// ============================================================================

typedef short v8s __attribute__((ext_vector_type(8)));
typedef int   v4i __attribute__((ext_vector_type(4)));
typedef float v4f __attribute__((ext_vector_type(4)));

#define B_  32
#define S_  2048
#define DH  512
#define SLOT32 16384                      // u32 per ring slot (32 x 512)
#define EPOCH4(q) ((unsigned)(((q) >> 2) & 7))

// ws layout (bytes)
#define BIAS_OFF  0                       // [2][512] f32 (b_ih + b_hh)
#define H0_OFF    8192                    // 4 slots x 64KB packed u32
#define H1_OFF    (H0_OFF + 4 * 65536)
#define WOUT_OFF  (H1_OFF + 4 * 65536)    // w_out bf16 [512][512]
#define WIH0_OFF  (WOUT_OFF + 524288)     // w_ih[0] bf16 [512][512]

#define PART_BYTES (8 * 3 * 4 * 64 * 16)  // 96KB LDS partials

static __device__ __forceinline__ unsigned short f2bf(float f) {  // RNE
  unsigned int u = __builtin_bit_cast(unsigned int, f);
  u += 0x7fffu + ((u >> 16) & 1u);
  return (unsigned short)(u >> 16);
}
static __device__ __forceinline__ float bf2f(unsigned short h) {
  return __builtin_bit_cast(float, ((unsigned int)h) << 16);
}
static __device__ __forceinline__ unsigned packh(float f, unsigned ep) {
  unsigned short hv = f2bf(f);
  unsigned short lv = f2bf(f - bf2f(hv));
  return ((unsigned)hv << 16) | ((unsigned)lv & 0xFFF8u) | ep;
}
static __device__ __forceinline__ v8s pack8(float4 f0, float4 f1) {
  v8s r;
  r[0] = (short)f2bf(f0.x); r[1] = (short)f2bf(f0.y);
  r[2] = (short)f2bf(f0.z); r[3] = (short)f2bf(f0.w);
  r[4] = (short)f2bf(f1.x); r[5] = (short)f2bf(f1.y);
  r[6] = (short)f2bf(f1.z); r[7] = (short)f2bf(f1.w);
  return r;
}
static __device__ __forceinline__ float fast_tanh(float v) {
  float c = fminf(15.f, fmaxf(-15.f, v));
  float e = __expf(2.f * c);
  return (e - 1.f) * __builtin_amdgcn_rcpf(e + 1.f);
}

// ---- device-scope (MALL) accessors ----------------------------------------
static __device__ __forceinline__ v4i ld16v(const unsigned* p) {
  v4i r;
  asm volatile("global_load_dwordx4 %0, %1, off sc1"
               : "=v"(r) : "v"(p) : "memory");
  return r;
}
static __device__ __forceinline__ float ld4(const void* p) {  // cached
  float r;
  asm volatile("global_load_dword %0, %1, off"
               : "=v"(r) : "v"(p) : "memory");
  return r;
}
static __device__ __forceinline__ void st32u(void* p, unsigned v) {
  asm volatile("global_store_dword %0, %1, off sc1"
               :: "v"(p), "v"(v) : "memory");
}
#define WAITN0() do { asm volatile("s_waitcnt vmcnt(0)" ::: "memory"); \
    __builtin_amdgcn_sched_barrier(0); } while (0)

// Full-fragment poll: detection and data in the same loads (r6 mechanism).
static __device__ __forceinline__ void poll_frag(const unsigned* b, unsigned ep,
                                                 bool* bad, v4i* o0, v4i* o1,
                                                 v4i* o2, v4i* o3) {
  v4i a0, a1, a2, a3;
  int t = 0;
  for (;;) {
    a0 = ld16v(b); a1 = ld16v(b + 4); a2 = ld16v(b + 32); a3 = ld16v(b + 36);
    WAITN0();
    if (*bad) break;
    unsigned d = 0;
    #pragma unroll
    for (int j = 0; j < 4; ++j)
      d |= ((unsigned)a0[j] ^ ep) | ((unsigned)a1[j] ^ ep)
         | ((unsigned)a2[j] ^ ep) | ((unsigned)a3[j] ^ ep);
    if (__all((d & 7u) == 0u)) break;
    if (++t > (1 << 15)) { *bad = true; break; }
  }
  *o0 = a0; *o1 = a1; *o2 = a2; *o3 = a3;
}
static __device__ __forceinline__ void unp(v4i a, v4i b, v8s* hi, v8s* lo) {
  v8s h, l;
  #pragma unroll
  for (int j = 0; j < 4; ++j) {
    unsigned ua = (unsigned)a[j], ub = (unsigned)b[j];
    h[j]     = (short)(ua >> 16);   l[j]     = (short)(ua & 0xFFF8u);
    h[4 + j] = (short)(ub >> 16);   l[4 + j] = (short)(ub & 0xFFF8u);
  }
  *hi = h; *lo = l;
}

// ---------------------------------------------------------------------------
__global__ void rnn_init(const float* __restrict__ hidden,
                         const float* __restrict__ b_ih,
                         const float* __restrict__ b_hh,
                         const float* __restrict__ w_out,
                         const float* __restrict__ w_ih,
                         float* __restrict__ bias,
                         unsigned* __restrict__ h0ring,
                         unsigned* __restrict__ h1ring,
                         unsigned short* __restrict__ woutbf,
                         unsigned short* __restrict__ wih0bf) {
  int i = blockIdx.x * blockDim.x + threadIdx.x;
  int nth = gridDim.x * blockDim.x;
  for (int t = i; t < 1024; t += nth) bias[t] = b_ih[t] + b_hh[t];
  for (int t = i; t < 2 * B_ * DH; t += nth) {     // initial h -> slot 3, tag 7
    int l = t >> 14;
    int off = t & 16383;
    unsigned* ring = l ? h1ring : h0ring;
    ring[3 * SLOT32 + off] = packh(hidden[t], 7u);
  }
  for (int t = i; t < 512 * 512; t += nth) {
    woutbf[t] = f2bf(w_out[t]);
    wih0bf[t] = f2bf(w_ih[t]);
  }
}

// ---------------------------------------------------------------------------
// Bulk projection: dst[r][:] = src[r][:] @ wb^T + bias (64 rows/WG, in-place ok)
__global__ __launch_bounds__(512) void proj64(
    const float* __restrict__ src,
    float* __restrict__ dst,
    const unsigned short* __restrict__ wb,
    const float* __restrict__ bias) {
  __shared__ unsigned short lds[64 * 512];
  const int tid = threadIdx.x;
  const int wid = tid >> 6;
  const int lane = tid & 63;
  const size_t row0 = (size_t)blockIdx.x * 64;

  #pragma unroll
  for (int it = 0; it < 8; ++it) {
    int c = it * 512 + tid;
    int row = c >> 6;
    int col8 = c & 63;
    const float4* s4 = (const float4*)(src + (row0 + row) * DH + col8 * 8);
    float4 f0 = s4[0], f1 = s4[1];
    v8s t = pack8(f0, f1);
    int byteoff = row * 1024 + ((col8 * 16) ^ ((row & 7) << 4));
    *(v8s*)((char*)lds + byteoff) = t;
  }
  __syncthreads();

  const int l15 = lane & 15;
  const int kq = (lane >> 4) * 8;

  for (int nt = wid; nt < 32; nt += 8) {
    v4f acc[4];
    #pragma unroll
    for (int mt = 0; mt < 4; ++mt) acc[mt] = (v4f){0.f, 0.f, 0.f, 0.f};
    const unsigned short* wr = wb + (size_t)(nt * 16 + l15) * 512;
    #pragma unroll
    for (int ks = 0; ks < 16; ++ks) {
      int kk = ks * 32 + kq;
      v8s bfrag = *(const v8s*)(wr + kk);
      #pragma unroll
      for (int mt = 0; mt < 4; ++mt) {
        int row = mt * 16 + l15;
        int byteoff = row * 1024 + ((kk * 2) ^ ((row & 7) << 4));
        v8s afrag = *(const v8s*)((char*)lds + byteoff);
        acc[mt] = __builtin_amdgcn_mfma_f32_16x16x32_bf16(afrag, bfrag, acc[mt], 0, 0, 0);
      }
    }
    float bo = bias[nt * 16 + l15];
    #pragma unroll
    for (int mt = 0; mt < 4; ++mt)
      #pragma unroll
      for (int r = 0; r < 4; ++r) {
        int row = mt * 16 + (lane >> 4) * 4 + r;
        int col = nt * 16 + l15;
        dst[(row0 + row) * DH + col] = acc[mt][r] + bo;
      }
  }
}

// ---------------------------------------------------------------------------
// Fused persistent kernel. wg = mh*8 + fs. 8 waves = 8 K-eighths.
// Finisher remap: wave w (w<4) owns batches 4w..4w+3, lane = feature ->
// contiguous 256B wave-stores for rings and dout.
__global__ __launch_bounds__(512) void rnn_fused(
    const float* __restrict__ z0,     // d_out: Z0 (overwritten by dout)
    const float* __restrict__ w_ih,
    const float* __restrict__ w_hh,
    const float* __restrict__ bias,
    unsigned* __restrict__ h0ring,
    unsigned* __restrict__ h1ring,
    float* __restrict__ dout) {
  extern __shared__ char smem[];
  v4f* part = (v4f*)smem;               // [8][3][4][64]

  const int wg = blockIdx.x;
  const int mh = wg >> 3;               // batch half
  const int fs = wg & 7;                // feature slice (64 feats)

  const int tid = threadIdx.x;
  const int wid = tid >> 6;             // K-eighth
  const int lane = tid & 63;
  const int l15 = lane & 15;
  const int kq = (lane >> 4) * 8;

  // resident weights: wfrag[g][n][ks], g: {w_hh0, w_ih1, w_hh1}
  v8s wfrag[3][4][2];
  {
    const float* wsrcs[3] = { w_hh, w_ih + 512 * 512, w_hh + 512 * 512 };
    #pragma unroll
    for (int g = 0; g < 3; ++g)
      #pragma unroll
      for (int n = 0; n < 4; ++n)
        #pragma unroll
        for (int ks = 0; ks < 2; ++ks) {
          const float* srow = wsrcs[g] +
              (size_t)(fs * 64 + n * 16 + l15) * 512 + wid * 64 + ks * 32 + kq;
          wfrag[g][n][ks] = pack8(*(const float4*)srow, *(const float4*)(srow + 4));
        }
  }
  const float biasl = bias[512 + fs * 64 + lane];   // finisher bias (lane=feat)
  const size_t abase = (size_t)(mh * 16 + l15) * 512 + wid * 64 + kq;
  // finisher geometry: wave wid<4 owns batches mh*16 + 4*wid + j, lane = feat
  const size_t fcol = (size_t)(fs * 64 + lane);

  bool bad = false;

  for (int p = 0; p <= S_; ++p) {
    const unsigned ep0 = (p == 0) ? 7u : EPOCH4(p - 1);
    const unsigned ep1 = (p == 1) ? 7u : EPOCH4(p - 2);
    const unsigned* h0b = h0ring + (size_t)((p + 3) & 3) * SLOT32 + abase;
    const unsigned* h1b = h1ring + (size_t)((p + 2) & 3) * SLOT32 + abase;

    // ---- early-issue h1(p-2) fragments (drain inside the h0 poll) --------
    v4i B0, B1, B2, B3;
    if (p >= 1) {
      B0 = ld16v(h1b); B1 = ld16v(h1b + 4);
      B2 = ld16v(h1b + 32); B3 = ld16v(h1b + 36);
    }

    // ---- poll h0(p-1): detection + data in one ----------------------------
    v4i A0, A1, A2, A3;
    poll_frag(h0b, ep0, &bad, &A0, &A1, &A2, &A3);

    // ---- verify early B tags (backstop) -----------------------------------
    if (p >= 1) {
      unsigned d = 0;
      #pragma unroll
      for (int j = 0; j < 4; ++j)
        d |= ((unsigned)B0[j] ^ ep1) | ((unsigned)B1[j] ^ ep1)
           | ((unsigned)B2[j] ^ ep1) | ((unsigned)B3[j] ^ ep1);
      if (!__all((d & 7u) == 0u))
        poll_frag(h1b, ep1, &bad, &B0, &B1, &B2, &B3);
    }

    // ---- z0 loads (coalesced, off the poll path; drained at finisher) ----
    float zp[4];
    if (wid < 4) {
      const int pz = (p < S_) ? p : (S_ - 1);
      #pragma unroll
      for (int j = 0; j < 4; ++j)
        zp[j] = ld4(z0 + ((size_t)(mh * 16 + 4 * wid + j) * S_ + pz) * DH + fcol);
    }

    v8s h0h0, h0l0, h0h1, h0l1;
    unp(A0, A1, &h0h0, &h0l0);
    unp(A2, A3, &h0h1, &h0l1);

    v4f acc0[4], acc1[4], acc2[4];
    #pragma unroll
    for (int n = 0; n < 4; ++n) {
      acc0[n] = (v4f){0.f, 0.f, 0.f, 0.f};
      acc1[n] = (v4f){0.f, 0.f, 0.f, 0.f};
      acc2[n] = (v4f){0.f, 0.f, 0.f, 0.f};
    }
    #pragma unroll
    for (int n = 0; n < 4; ++n) {
      acc0[n] = __builtin_amdgcn_mfma_f32_16x16x32_bf16(h0h0, wfrag[0][n][0], acc0[n], 0, 0, 0);
      acc0[n] = __builtin_amdgcn_mfma_f32_16x16x32_bf16(h0l0, wfrag[0][n][0], acc0[n], 0, 0, 0);
      acc0[n] = __builtin_amdgcn_mfma_f32_16x16x32_bf16(h0h1, wfrag[0][n][1], acc0[n], 0, 0, 0);
      acc0[n] = __builtin_amdgcn_mfma_f32_16x16x32_bf16(h0l1, wfrag[0][n][1], acc0[n], 0, 0, 0);
      acc1[n] = __builtin_amdgcn_mfma_f32_16x16x32_bf16(h0h0, wfrag[1][n][0], acc1[n], 0, 0, 0);
      acc1[n] = __builtin_amdgcn_mfma_f32_16x16x32_bf16(h0l0, wfrag[1][n][0], acc1[n], 0, 0, 0);
      acc1[n] = __builtin_amdgcn_mfma_f32_16x16x32_bf16(h0h1, wfrag[1][n][1], acc1[n], 0, 0, 0);
      acc1[n] = __builtin_amdgcn_mfma_f32_16x16x32_bf16(h0l1, wfrag[1][n][1], acc1[n], 0, 0, 0);
    }
    if (p >= 1) {
      v8s h1h0, h1l0, h1h1, h1l1;
      unp(B0, B1, &h1h0, &h1l0);
      unp(B2, B3, &h1h1, &h1l1);
      #pragma unroll
      for (int n = 0; n < 4; ++n) {
        acc2[n] = __builtin_amdgcn_mfma_f32_16x16x32_bf16(h1h0, wfrag[2][n][0], acc2[n], 0, 0, 0);
        acc2[n] = __builtin_amdgcn_mfma_f32_16x16x32_bf16(h1l0, wfrag[2][n][0], acc2[n], 0, 0, 0);
        acc2[n] = __builtin_amdgcn_mfma_f32_16x16x32_bf16(h1h1, wfrag[2][n][1], acc2[n], 0, 0, 0);
        acc2[n] = __builtin_amdgcn_mfma_f32_16x16x32_bf16(h1l1, wfrag[2][n][1], acc2[n], 0, 0, 0);
      }
    }

    // ---- K-reduction partials ---------------------------------------------
    #pragma unroll
    for (int n = 0; n < 4; ++n) {
      part[((wid * 3 + 0) * 4 + n) * 64 + lane] = acc0[n];
      part[((wid * 3 + 1) * 4 + n) * 64 + lane] = acc1[n];
      part[((wid * 3 + 2) * 4 + n) * 64 + lane] = acc2[n];
    }
    __syncthreads();

    // ---- finishers (remapped): reduce, tanh, CONTIGUOUS 256B stores -------
    if (wid < 4) {
      WAITN0();                              // zp complete (long since)
      // lane=feat: n=lane>>4, c=lane&15; v4f elements j = batches 4*wid+j
      const int pidx = (wid * 16 + (lane & 15)) + (lane >> 4) * 64;
      v4f s0 = {0.f,0.f,0.f,0.f}, s1 = {0.f,0.f,0.f,0.f}, s2 = {0.f,0.f,0.f,0.f};
      #pragma unroll
      for (int kw = 0; kw < 8; ++kw) {
        s0 += part[(kw * 3 + 0) * 256 + pidx];
        s1 += part[(kw * 3 + 1) * 256 + pidx];
        s2 += part[(kw * 3 + 2) * 256 + pidx];
      }
      float h0v[4], h1v[4];
      #pragma unroll
      for (int j = 0; j < 4; ++j) {
        h0v[j] = fast_tanh(zp[j] + s0[j]);
        h1v[j] = fast_tanh(s1[j] + s2[j] + biasl);
      }
      if (p < S_) {                          // h0(p): 4 contiguous wave-stores
        const unsigned ep = EPOCH4(p);
        unsigned* dst = h0ring + (size_t)(p & 3) * SLOT32;
        #pragma unroll
        for (int j = 0; j < 4; ++j)
          st32u(dst + (size_t)(mh * 16 + 4 * wid + j) * 512 + fcol,
                packh(h0v[j], ep));
      }
      if (p >= 1) {                          // h1(p-1) + dout, contiguous
        const unsigned ep = EPOCH4(p - 1);
        unsigned* dst = h1ring + (size_t)((p - 1) & 3) * SLOT32;
        #pragma unroll
        for (int j = 0; j < 4; ++j) {
          st32u(dst + (size_t)(mh * 16 + 4 * wid + j) * 512 + fcol,
                packh(h1v[j], ep));
          dout[((size_t)(mh * 16 + 4 * wid + j) * S_ + (p - 1)) * DH + fcol] = h1v[j];
        }
      }
    }
    __syncthreads();   // keep LDS partials stable until finishers consumed them
  }
}

// ---------------------------------------------------------------------------
extern "C" void kernel_launch(void* const* d_in, const int* in_sizes, int n_in,
                              void* d_out, int out_size, void* d_ws, size_t ws_size,
                              hipStream_t stream) {
  const float* x      = (const float*)d_in[0];
  const float* hidden = (const float*)d_in[1];
  const float* w_ih   = (const float*)d_in[2];
  const float* w_hh   = (const float*)d_in[3];
  const float* b_ih   = (const float*)d_in[4];
  const float* b_hh   = (const float*)d_in[5];
  const float* w_out  = (const float*)d_in[6];
  const float* b_out  = (const float*)d_in[7];
  float* out = (float*)d_out;

  char* wsb = (char*)d_ws;
  float* bias            = (float*)(wsb + BIAS_OFF);
  unsigned* h0ring       = (unsigned*)(wsb + H0_OFF);
  unsigned* h1ring       = (unsigned*)(wsb + H1_OFF);
  unsigned short* woutbf = (unsigned short*)(wsb + WOUT_OFF);
  unsigned short* wih0bf = (unsigned short*)(wsb + WIH0_OFF);

  rnn_init<<<256, 256, 0, stream>>>(hidden, b_ih, b_hh, w_out, w_ih,
                                    bias, h0ring, h1ring, woutbf, wih0bf);
  // Z0 = x @ w_ih0^T + (b_ih0 + b_hh0) -> d_out
  proj64<<<(B_ * S_) / 64, 512, 0, stream>>>(x, out, wih0bf, bias);
  rnn_fused<<<16, 512, PART_BYTES, stream>>>(out, w_ih, w_hh, bias,
                                             h0ring, h1ring, out);
  // out = h1 @ w_out^T + b_out (in place)
  proj64<<<(B_ * S_) / 64, 512, 0, stream>>>(out, out, woutbf, b_out);
}

// Round 13
// 7245.312 us; speedup vs baseline: 1.3028x; 1.1726x over previous
//
#include <hip/hip_runtime.h>

// ============================================================================
// 2-layer tanh RNN, B=32, S=2048, D=H=O=512.
//  r12 = r6 skeleton EXACTLY (best: 6.95ms) with ONE change:
//   ring stores go through no-return global_atomic_swap instead of sc1
//   stores. Evidence (r11 counters): FETCH 1.06GB / WRITE 393MB => sc1
//   stores are write-through NO-ALLOCATE, so every sync leg was an HBM
//   round trip. Far atomics execute at the MALL's memory-side ALUs -> the
//   ring line is allocated/dirty in MALL; consumer sc1 polls are then
//   MALL hits. Predicted: FETCH craters, step time ~halves or better.
// ============================================================================

typedef short v8s __attribute__((ext_vector_type(8)));
typedef int   v4i __attribute__((ext_vector_type(4)));
typedef float v4f __attribute__((ext_vector_type(4)));

#define B_  32
#define S_  2048
#define DH  512
#define SLOT32 16384                      // u32 per ring slot (32 x 512)
#define EPOCH4(q) ((unsigned)(((q) >> 2) & 7))

// ws layout (bytes)
#define BIAS_OFF  0                       // [2][512] f32 (b_ih + b_hh)
#define H0_OFF    8192                    // 4 slots x 64KB packed u32
#define H1_OFF    (H0_OFF + 4 * 65536)
#define WOUT_OFF  (H1_OFF + 4 * 65536)    // w_out bf16 [512][512]
#define WIH0_OFF  (WOUT_OFF + 524288)     // w_ih[0] bf16 [512][512]

#define PART_BYTES (8 * 3 * 4 * 64 * 16)  // 96KB LDS partials

static __device__ __forceinline__ unsigned short f2bf(float f) {  // RNE
  unsigned int u = __builtin_bit_cast(unsigned int, f);
  u += 0x7fffu + ((u >> 16) & 1u);
  return (unsigned short)(u >> 16);
}
static __device__ __forceinline__ float bf2f(unsigned short h) {
  return __builtin_bit_cast(float, ((unsigned int)h) << 16);
}
static __device__ __forceinline__ unsigned packh(float f, unsigned ep) {
  unsigned short hv = f2bf(f);
  unsigned short lv = f2bf(f - bf2f(hv));
  return ((unsigned)hv << 16) | ((unsigned)lv & 0xFFF8u) | ep;
}
static __device__ __forceinline__ v8s pack8(float4 f0, float4 f1) {
  v8s r;
  r[0] = (short)f2bf(f0.x); r[1] = (short)f2bf(f0.y);
  r[2] = (short)f2bf(f0.z); r[3] = (short)f2bf(f0.w);
  r[4] = (short)f2bf(f1.x); r[5] = (short)f2bf(f1.y);
  r[6] = (short)f2bf(f1.z); r[7] = (short)f2bf(f1.w);
  return r;
}
static __device__ __forceinline__ float fast_tanh(float v) {
  float c = fminf(15.f, fmaxf(-15.f, v));
  float e = __expf(2.f * c);
  return (e - 1.f) * __builtin_amdgcn_rcpf(e + 1.f);
}

// ---- device-scope accessors -------------------------------------------------
static __device__ __forceinline__ v4i ld16v(const unsigned* p) {
  v4i r;
  asm volatile("global_load_dwordx4 %0, %1, off sc1"
               : "=v"(r) : "v"(p) : "memory");
  return r;
}
static __device__ __forceinline__ float ld4(const void* p) {  // cached, counted
  float r;
  asm volatile("global_load_dword %0, %1, off"
               : "=v"(r) : "v"(p) : "memory");
  return r;
}
// Ring store via far atomic: executes at the MALL -> line allocated there.
static __device__ __forceinline__ void atom_swap(void* p, unsigned v) {
  asm volatile("global_atomic_swap %0, %1, off"
               :: "v"(p), "v"(v) : "memory");
}
#define WAITN0() do { asm volatile("s_waitcnt vmcnt(0)" ::: "memory"); \
    __builtin_amdgcn_sched_barrier(0); } while (0)

// Poll one matrix fragment set (16 u32/lane): detection + data in one.
static __device__ __forceinline__ void poll_frag(const unsigned* b, unsigned ep,
                                                 bool* bad, v4i* o0, v4i* o1,
                                                 v4i* o2, v4i* o3) {
  v4i a0, a1, a2, a3;
  int t = 0;
  for (;;) {
    a0 = ld16v(b); a1 = ld16v(b + 4); a2 = ld16v(b + 32); a3 = ld16v(b + 36);
    WAITN0();
    if (*bad) break;
    unsigned d = 0;
    #pragma unroll
    for (int j = 0; j < 4; ++j)
      d |= ((unsigned)a0[j] ^ ep) | ((unsigned)a1[j] ^ ep)
         | ((unsigned)a2[j] ^ ep) | ((unsigned)a3[j] ^ ep);
    if (__all((d & 7u) == 0u)) break;
    if (++t > (1 << 15)) { *bad = true; break; }
  }
  *o0 = a0; *o1 = a1; *o2 = a2; *o3 = a3;
}
static __device__ __forceinline__ void unp(v4i a, v4i b, v8s* hi, v8s* lo) {
  v8s h, l;
  #pragma unroll
  for (int j = 0; j < 4; ++j) {
    unsigned ua = (unsigned)a[j], ub = (unsigned)b[j];
    h[j]     = (short)(ua >> 16);   l[j]     = (short)(ua & 0xFFF8u);
    h[4 + j] = (short)(ub >> 16);   l[4 + j] = (short)(ub & 0xFFF8u);
  }
  *hi = h; *lo = l;
}

// ---------------------------------------------------------------------------
__global__ void rnn_init(const float* __restrict__ hidden,
                         const float* __restrict__ b_ih,
                         const float* __restrict__ b_hh,
                         const float* __restrict__ w_out,
                         const float* __restrict__ w_ih,
                         float* __restrict__ bias,
                         unsigned* __restrict__ h0ring,
                         unsigned* __restrict__ h1ring,
                         unsigned short* __restrict__ woutbf,
                         unsigned short* __restrict__ wih0bf) {
  int i = blockIdx.x * blockDim.x + threadIdx.x;
  int nth = gridDim.x * blockDim.x;
  for (int t = i; t < 1024; t += nth) bias[t] = b_ih[t] + b_hh[t];
  for (int t = i; t < 2 * B_ * DH; t += nth) {     // initial h -> slot 3, tag 7
    int l = t >> 14;
    int off = t & 16383;
    unsigned* ring = l ? h1ring : h0ring;
    atom_swap(ring + 3 * SLOT32 + off, packh(hidden[t], 7u));
  }
  for (int t = i; t < 512 * 512; t += nth) {
    woutbf[t] = f2bf(w_out[t]);
    wih0bf[t] = f2bf(w_ih[t]);
  }
}

// ---------------------------------------------------------------------------
// Bulk projection: dst[r][:] = src[r][:] @ wb^T + bias (64 rows/WG, in-place ok)
__global__ __launch_bounds__(512) void proj64(
    const float* __restrict__ src,
    float* __restrict__ dst,
    const unsigned short* __restrict__ wb,
    const float* __restrict__ bias) {
  __shared__ unsigned short lds[64 * 512];
  const int tid = threadIdx.x;
  const int wid = tid >> 6;
  const int lane = tid & 63;
  const size_t row0 = (size_t)blockIdx.x * 64;

  #pragma unroll
  for (int it = 0; it < 8; ++it) {
    int c = it * 512 + tid;
    int row = c >> 6;
    int col8 = c & 63;
    const float4* s4 = (const float4*)(src + (row0 + row) * DH + col8 * 8);
    float4 f0 = s4[0], f1 = s4[1];
    v8s t = pack8(f0, f1);
    int byteoff = row * 1024 + ((col8 * 16) ^ ((row & 7) << 4));
    *(v8s*)((char*)lds + byteoff) = t;
  }
  __syncthreads();

  const int l15 = lane & 15;
  const int kq = (lane >> 4) * 8;

  for (int nt = wid; nt < 32; nt += 8) {
    v4f acc[4];
    #pragma unroll
    for (int mt = 0; mt < 4; ++mt) acc[mt] = (v4f){0.f, 0.f, 0.f, 0.f};
    const unsigned short* wr = wb + (size_t)(nt * 16 + l15) * 512;
    #pragma unroll
    for (int ks = 0; ks < 16; ++ks) {
      int kk = ks * 32 + kq;
      v8s bfrag = *(const v8s*)(wr + kk);
      #pragma unroll
      for (int mt = 0; mt < 4; ++mt) {
        int row = mt * 16 + l15;
        int byteoff = row * 1024 + ((kk * 2) ^ ((row & 7) << 4));
        v8s afrag = *(const v8s*)((char*)lds + byteoff);
        acc[mt] = __builtin_amdgcn_mfma_f32_16x16x32_bf16(afrag, bfrag, acc[mt], 0, 0, 0);
      }
    }
    float bo = bias[nt * 16 + l15];
    #pragma unroll
    for (int mt = 0; mt < 4; ++mt)
      #pragma unroll
      for (int r = 0; r < 4; ++r) {
        int row = mt * 16 + (lane >> 4) * 4 + r;
        int col = nt * 16 + l15;
        dst[(row0 + row) * DH + col] = acc[mt][r] + bo;
      }
  }
}

// ---------------------------------------------------------------------------
// Fused persistent kernel. wg = mh*8 + fs. 8 waves = 8 K-eighths.
// Phase p: GEMM0 Whh0*h0(p-1) -> h0(p); GEMM1 Wih1*h0(p-1) and
// GEMM2 Whh1*h1(p-2) -> h1(p-1). Waves 0-3 finish (reduce+tanh+store).
__global__ __launch_bounds__(512) void rnn_fused(
    const float* __restrict__ z0,     // d_out: Z0 (overwritten by dout)
    const float* __restrict__ w_ih,
    const float* __restrict__ w_hh,
    const float* __restrict__ bias,
    unsigned* __restrict__ h0ring,
    unsigned* __restrict__ h1ring,
    float* __restrict__ dout) {
  extern __shared__ char smem[];
  v4f* part = (v4f*)smem;               // [8][3][4][64]

  const int wg = blockIdx.x;
  const int mh = wg >> 3;               // batch half
  const int fs = wg & 7;                // feature slice (64 feats)

  const int tid = threadIdx.x;
  const int wid = tid >> 6;             // K-eighth
  const int lane = tid & 63;
  const int l15 = lane & 15;
  const int kq = (lane >> 4) * 8;
  const int q4 = (lane >> 4) * 4;

  // resident weights: wfrag[g][n][ks], g: {w_hh0, w_ih1, w_hh1}
  v8s wfrag[3][4][2];
  {
    const float* wsrcs[3] = { w_hh, w_ih + 512 * 512, w_hh + 512 * 512 };
    #pragma unroll
    for (int g = 0; g < 3; ++g)
      #pragma unroll
      for (int n = 0; n < 4; ++n)
        #pragma unroll
        for (int ks = 0; ks < 2; ++ks) {
          const float* srow = wsrcs[g] +
              (size_t)(fs * 64 + n * 16 + l15) * 512 + wid * 64 + ks * 32 + kq;
          wfrag[g][n][ks] = pack8(*(const float4*)srow, *(const float4*)(srow + 4));
        }
  }
  const int nf = wid & 3;               // finisher n-tile (wid<4)
  const float bias1v = bias[512 + fs * 64 + nf * 16 + l15];
  const size_t abase = (size_t)(mh * 16 + l15) * 512 + wid * 64 + kq;
  const int featf = fs * 64 + nf * 16 + l15;

  bool bad = false;

  for (int p = 0; p <= S_; ++p) {
    // ---- z0 issue (finishers; drains inside first poll wait) --------------
    float zp[4];
    if (wid < 4) {
      const int pz = (p < S_) ? p : (S_ - 1);
      #pragma unroll
      for (int r = 0; r < 4; ++r)
        zp[r] = ld4(z0 + ((size_t)(mh * 16 + q4 + r) * S_ + pz) * DH + featf);
    }

    // ---- poll h0(p-1), GEMM0/1 --------------------------------------------
    const unsigned ep0 = (p == 0) ? 7u : EPOCH4(p - 1);
    const unsigned* h0b = h0ring + (size_t)((p + 3) & 3) * SLOT32 + abase;
    v4i A0, A1, A2, A3;
    poll_frag(h0b, ep0, &bad, &A0, &A1, &A2, &A3);
    v8s h0h0, h0l0, h0h1, h0l1;
    unp(A0, A1, &h0h0, &h0l0);
    unp(A2, A3, &h0h1, &h0l1);

    v4f acc0[4], acc1[4], acc2[4];
    #pragma unroll
    for (int n = 0; n < 4; ++n) {
      acc0[n] = (v4f){0.f, 0.f, 0.f, 0.f};
      acc1[n] = (v4f){0.f, 0.f, 0.f, 0.f};
      acc2[n] = (v4f){0.f, 0.f, 0.f, 0.f};
    }
    #pragma unroll
    for (int n = 0; n < 4; ++n) {
      acc0[n] = __builtin_amdgcn_mfma_f32_16x16x32_bf16(h0h0, wfrag[0][n][0], acc0[n], 0, 0, 0);
      acc0[n] = __builtin_amdgcn_mfma_f32_16x16x32_bf16(h0l0, wfrag[0][n][0], acc0[n], 0, 0, 0);
      acc0[n] = __builtin_amdgcn_mfma_f32_16x16x32_bf16(h0h1, wfrag[0][n][1], acc0[n], 0, 0, 0);
      acc0[n] = __builtin_amdgcn_mfma_f32_16x16x32_bf16(h0l1, wfrag[0][n][1], acc0[n], 0, 0, 0);
      acc1[n] = __builtin_amdgcn_mfma_f32_16x16x32_bf16(h0h0, wfrag[1][n][0], acc1[n], 0, 0, 0);
      acc1[n] = __builtin_amdgcn_mfma_f32_16x16x32_bf16(h0l0, wfrag[1][n][0], acc1[n], 0, 0, 0);
      acc1[n] = __builtin_amdgcn_mfma_f32_16x16x32_bf16(h0h1, wfrag[1][n][1], acc1[n], 0, 0, 0);
      acc1[n] = __builtin_amdgcn_mfma_f32_16x16x32_bf16(h0l1, wfrag[1][n][1], acc1[n], 0, 0, 0);
    }

    // ---- poll h1(p-2), GEMM2 (skip at p==0: result discarded) -------------
    if (p >= 1) {
      const unsigned ep1 = (p == 1) ? 7u : EPOCH4(p - 2);
      const unsigned* h1b = h1ring + (size_t)((p + 2) & 3) * SLOT32 + abase;
      v4i B0, B1, B2, B3;
      poll_frag(h1b, ep1, &bad, &B0, &B1, &B2, &B3);
      v8s h1h0, h1l0, h1h1, h1l1;
      unp(B0, B1, &h1h0, &h1l0);
      unp(B2, B3, &h1h1, &h1l1);
      #pragma unroll
      for (int n = 0; n < 4; ++n) {
        acc2[n] = __builtin_amdgcn_mfma_f32_16x16x32_bf16(h1h0, wfrag[2][n][0], acc2[n], 0, 0, 0);
        acc2[n] = __builtin_amdgcn_mfma_f32_16x16x32_bf16(h1l0, wfrag[2][n][0], acc2[n], 0, 0, 0);
        acc2[n] = __builtin_amdgcn_mfma_f32_16x16x32_bf16(h1h1, wfrag[2][n][1], acc2[n], 0, 0, 0);
        acc2[n] = __builtin_amdgcn_mfma_f32_16x16x32_bf16(h1l1, wfrag[2][n][1], acc2[n], 0, 0, 0);
      }
    }

    // ---- K-reduction partials ---------------------------------------------
    #pragma unroll
    for (int n = 0; n < 4; ++n) {
      part[((wid * 3 + 0) * 4 + n) * 64 + lane] = acc0[n];
      part[((wid * 3 + 1) * 4 + n) * 64 + lane] = acc1[n];
      part[((wid * 3 + 2) * 4 + n) * 64 + lane] = acc2[n];
    }
    __syncthreads();

    // ---- finishers: reduce, tanh, pack+tag, fire-and-forget ATOMIC stores --
    if (wid < 4) {
      v4f s0 = {0.f,0.f,0.f,0.f}, s1 = {0.f,0.f,0.f,0.f}, s2 = {0.f,0.f,0.f,0.f};
      #pragma unroll
      for (int w = 0; w < 8; ++w) {
        s0 += part[((w * 3 + 0) * 4 + nf) * 64 + lane];
        s1 += part[((w * 3 + 1) * 4 + nf) * 64 + lane];
        s2 += part[((w * 3 + 2) * 4 + nf) * 64 + lane];
      }
      float h0v[4], h1v[4];
      #pragma unroll
      for (int r = 0; r < 4; ++r) {
        h0v[r] = fast_tanh(zp[r] + s0[r]);
        h1v[r] = fast_tanh(s1[r] + s2[r] + bias1v);
      }
      if (p < S_) {                                   // h0(p), tag (p>>2)&7
        const unsigned ep = EPOCH4(p);
        unsigned* dst = h0ring + (size_t)(p & 3) * SLOT32;
        #pragma unroll
        for (int r = 0; r < 4; ++r)
          atom_swap(dst + (size_t)(mh * 16 + q4 + r) * 512 + featf,
                    packh(h0v[r], ep));
      }
      if (p >= 1) {                                   // h1(p-1), tag ((p-1)>>2)&7
        const unsigned ep = EPOCH4(p - 1);
        unsigned* dst = h1ring + (size_t)((p - 1) & 3) * SLOT32;
        #pragma unroll
        for (int r = 0; r < 4; ++r) {
          atom_swap(dst + (size_t)(mh * 16 + q4 + r) * 512 + featf,
                    packh(h1v[r], ep));
          dout[((size_t)(mh * 16 + q4 + r) * S_ + (p - 1)) * DH + featf] = h1v[r];
        }
      }
    }
    __syncthreads();   // keep LDS partials stable until finishers consumed them
  }
}

// ---------------------------------------------------------------------------
extern "C" void kernel_launch(void* const* d_in, const int* in_sizes, int n_in,
                              void* d_out, int out_size, void* d_ws, size_t ws_size,
                              hipStream_t stream) {
  const float* x      = (const float*)d_in[0];
  const float* hidden = (const float*)d_in[1];
  const float* w_ih   = (const float*)d_in[2];
  const float* w_hh   = (const float*)d_in[3];
  const float* b_ih   = (const float*)d_in[4];
  const float* b_hh   = (const float*)d_in[5];
  const float* w_out  = (const float*)d_in[6];
  const float* b_out  = (const float*)d_in[7];
  float* out = (float*)d_out;

  char* wsb = (char*)d_ws;
  float* bias            = (float*)(wsb + BIAS_OFF);
  unsigned* h0ring       = (unsigned*)(wsb + H0_OFF);
  unsigned* h1ring       = (unsigned*)(wsb + H1_OFF);
  unsigned short* woutbf = (unsigned short*)(wsb + WOUT_OFF);
  unsigned short* wih0bf = (unsigned short*)(wsb + WIH0_OFF);

  rnn_init<<<256, 256, 0, stream>>>(hidden, b_ih, b_hh, w_out, w_ih,
                                    bias, h0ring, h1ring, woutbf, wih0bf);
  // Z0 = x @ w_ih0^T + (b_ih0 + b_hh0) -> d_out
  proj64<<<(B_ * S_) / 64, 512, 0, stream>>>(x, out, wih0bf, bias);
  rnn_fused<<<16, 512, PART_BYTES, stream>>>(out, w_ih, w_hh, bias,
                                             h0ring, h1ring, out);
  // out = h1 @ w_out^T + b_out (in place)
  proj64<<<(B_ * S_) / 64, 512, 0, stream>>>(out, out, woutbf, b_out);
}